// Round 1
// baseline (850.503 us; speedup 1.0000x reference)
//
#include <hip/hip_runtime.h>

// RotationGate on qubit 0 (most-significant axis) of a 22-qubit state,
// batch 16, fp32. Pure streaming: 1.07 GB traffic -> HBM-bound (~170us floor).
//
// state_re/state_im: (DIM, B) row-major, B=16 -> one row = 4 float4s.
// out: (2, DIM, B): out[0]=real, out[1]=imag.
//
// Pairing: top row k in [0, DIM/2) pairs with bottom row k + DIM/2.
// In float4 units: top index t in [0, H4), bottom index t + H4,
// where H4 = (DIM/2)*16/4 = 8388608.

#define DIM   4194304   // 2^22
#define BATCH 16
#define H4    8388608   // (DIM/2)*BATCH/4 : float4 count of half the state
#define OUT_IMAG_OFF 16777216  // DIM*BATCH/4 : float4 offset of imag plane

__global__ __launch_bounds__(256) void rot_gate_kernel(
    const float* __restrict__ theta,
    const float4* __restrict__ re,
    const float4* __restrict__ im,
    float4* __restrict__ out)
{
    __shared__ float cs[BATCH];
    __shared__ float sn[BATCH];
    if (threadIdx.x < BATCH) {
        float t = theta[threadIdx.x] * 0.5f;
        cs[threadIdx.x] = __cosf(t) == __cosf(t) ? cosf(t) : cosf(t); // keep precise cosf
        sn[threadIdx.x] = sinf(t);
        cs[threadIdx.x] = cosf(t);
    }
    __syncthreads();

    unsigned tid = blockIdx.x * 256u + threadIdx.x;   // float4 index in top half
    unsigned q = tid & 3u;                            // which float4 of the row (b group)

    const float4* c4 = (const float4*)cs;
    const float4* s4 = (const float4*)sn;
    float4 c = c4[q];
    float4 s = s4[q];

    float4 r0 = re[tid];
    float4 i0 = im[tid];
    float4 r1 = re[tid + H4];
    float4 i1 = im[tid + H4];

    float4 o;
    // real top: c*r0 + s*i1
    o.x = c.x * r0.x + s.x * i1.x;
    o.y = c.y * r0.y + s.y * i1.y;
    o.z = c.z * r0.z + s.z * i1.z;
    o.w = c.w * r0.w + s.w * i1.w;
    out[tid] = o;

    // real bottom: c*r1 + s*i0
    o.x = c.x * r1.x + s.x * i0.x;
    o.y = c.y * r1.y + s.y * i0.y;
    o.z = c.z * r1.z + s.z * i0.z;
    o.w = c.w * r1.w + s.w * i0.w;
    out[tid + H4] = o;

    // imag top: c*i0 - s*r1
    o.x = c.x * i0.x - s.x * r1.x;
    o.y = c.y * i0.y - s.y * r1.y;
    o.z = c.z * i0.z - s.z * r1.z;
    o.w = c.w * i0.w - s.w * r1.w;
    out[tid + OUT_IMAG_OFF] = o;

    // imag bottom: c*i1 - s*r0
    o.x = c.x * i1.x - s.x * r0.x;
    o.y = c.y * i1.y - s.y * r0.y;
    o.z = c.z * i1.z - s.z * r0.z;
    o.w = c.w * i1.w - s.w * r0.w;
    out[tid + OUT_IMAG_OFF + H4] = o;
}

extern "C" void kernel_launch(void* const* d_in, const int* in_sizes, int n_in,
                              void* d_out, int out_size, void* d_ws, size_t ws_size,
                              hipStream_t stream) {
    const float*  theta = (const float*)d_in[0];
    const float4* re    = (const float4*)d_in[1];
    const float4* im    = (const float4*)d_in[2];
    float4* out = (float4*)d_out;

    // H4 work items (one float4 of the top half each), 256 threads/block
    dim3 grid(H4 / 256);
    rot_gate_kernel<<<grid, 256, 0, stream>>>(theta, re, im, out);
}